// Round 15
// baseline (116.178 us; speedup 1.0000x reference)
//
#include <hip/hip_runtime.h>

#define D256 256
#define S_SEQ 1024
#define OUTSEQ 512

typedef __attribute__((ext_vector_type(8))) short bf16x8;
typedef __attribute__((ext_vector_type(8))) unsigned short u16x8;
typedef __attribute__((ext_vector_type(4))) unsigned short u16x4;
typedef __attribute__((ext_vector_type(4))) float f32x4;
typedef __attribute__((ext_vector_type(2))) float f32x2;

// DIAGNOSTIC ROUND: all grids x4, blk = blockIdx.x % base. Duplicate blocks
// write identical values to identical addresses (deterministic). dur = OH + 4K.

__device__ inline unsigned short f2bf(float f) {          // RNE fp32->bf16
  unsigned u = __float_as_uint(f);
  return (unsigned short)((u + 0x7fffu + ((u >> 16) & 1u)) >> 16);
}

// ---------------- prep ----------------
__global__ __launch_bounds__(256) void k_prep(const float* __restrict__ x,
                                              const float* __restrict__ M,
                                              const float* __restrict__ resW,
                                              const float* __restrict__ P,
                                              const float* __restrict__ Linker,
                                              const float* __restrict__ rLinker,
                                              float4* __restrict__ PIt4,
                                              unsigned short* __restrict__ LinkTb,
                                              unsigned short* __restrict__ xb,
                                              unsigned short* __restrict__ Mb,
                                              unsigned short* __restrict__ Wb) {
  __shared__ float tl[64][65];
  const int tid = threadIdx.x;
  const int blk = blockIdx.x % 832;     // x4 duplication
  if (blk < 256) {
    const int j = blk;
    const int t = tid;
    const float p = (float)(t * D256 + j + 2);
    const float ip = 1.0f / p;
    const float cb2 = 2.0f * __builtin_amdgcn_cosf(ip);   // v_cos takes revolutions
    const float D = fmaf(cb2, cb2, -2.0f);                // 2cos(4pi/p)
    PIt4[j * D256 + t] = make_float4(P[t * D256 + j], ip, cb2, D);
    return;
  }
  if (blk >= 512) {                     // flat fp32 -> bf16 converts
    const float* src;
    unsigned short* dst;
    size_t base;
    if (blk < 768)      { src = x;    dst = xb; base = (size_t)(blk - 512) * 2048; }
    else if (blk < 800) { src = M;    dst = Mb; base = (size_t)(blk - 768) * 2048; }
    else                { src = resW; dst = Wb; base = (size_t)(blk - 800) * 2048; }
    const size_t off = base + (size_t)tid * 8;
    const float4 v0 = *(const float4*)(src + off);
    const float4 v1 = *(const float4*)(src + off + 4);
    u16x8 o;
    o[0] = f2bf(v0.x); o[1] = f2bf(v0.y); o[2] = f2bf(v0.z); o[3] = f2bf(v0.w);
    o[4] = f2bf(v1.x); o[5] = f2bf(v1.y); o[6] = f2bf(v1.z); o[7] = f2bf(v1.w);
    *(u16x8*)(dst + off) = o;
    return;
  }
  // LinkTb transpose-pack
  const int tb = blk - 256;
  const int st = tb & 31;
  const int tt = tb >> 5;
  const int s0 = st * 64, t0 = tt * 64;
  const float* src = (s0 < 1024) ? (Linker + (size_t)s0 * OUTSEQ)
                                 : (rLinker + (size_t)(s0 - 1024) * OUTSEQ);
  {
    const int sy = tid >> 2, sx = tid & 3;
    #pragma unroll
    for (int c = 0; c < 4; ++c) {
      const int ci = sx + c * 4;
      const float4 v = *(const float4*)&src[sy * OUTSEQ + t0 + ci * 4];
      tl[ci * 4 + 0][sy] = v.x;
      tl[ci * 4 + 1][sy] = v.y;
      tl[ci * 4 + 2][sy] = v.z;
      tl[ci * 4 + 3][sy] = v.w;
    }
  }
  __syncthreads();
  {
    const int ty = tid >> 2, tx = tid & 3;
    u16x8 o0, o1;
    #pragma unroll
    for (int e = 0; e < 8; ++e) o0[e] = f2bf(tl[ty][tx * 16 + e]);
    #pragma unroll
    for (int e = 0; e < 8; ++e) o1[e] = f2bf(tl[ty][tx * 16 + 8 + e]);
    unsigned short* dst = LinkTb + (size_t)(t0 + ty) * 2048 + s0 + tx * 16;
    *(u16x8*)dst = o0;
    *(u16x8*)(dst + 8) = o1;
  }
}

// ---------------- k_Azn: MFMA phase A + LN ----------------
__global__ __launch_bounds__(256) void k_Azn(const unsigned short* __restrict__ xb,
                                             const unsigned short* __restrict__ Mb,
                                             const unsigned short* __restrict__ Wb,
                                             const float* __restrict__ gamma,
                                             const float* __restrict__ beta,
                                             float* __restrict__ Zb,
                                             unsigned short* __restrict__ Bt) {
  __shared__ float Zs[16][D256];
  __shared__ float Rs[16][D256];
  __shared__ float mu_s[16], rs_s[16];
  const int k0 = (blockIdx.x & 127) * 16;   // x4 duplication
  const int w = threadIdx.x >> 6;
  const int l = threadIdx.x & 63;
  const int m = l & 15, q = l >> 4;

  f32x4 aZ[4] = {}, aR[4] = {};
  const unsigned short* Arow = xb + (size_t)(k0 + m) * D256;
  #pragma unroll
  for (int ks = 0; ks < 8; ++ks) {
    const bf16x8 a = *(const bf16x8*)(Arow + ks * 32 + q * 8);
    #pragma unroll
    for (int cf = 0; cf < 4; ++cf) {
      const int o = w * 64 + cf * 16 + m;
      const bf16x8 bz = *(const bf16x8*)(Mb + (size_t)o * D256 + ks * 32 + q * 8);
      const bf16x8 br = *(const bf16x8*)(Wb + (size_t)o * D256 + ks * 32 + q * 8);
      aZ[cf] = __builtin_amdgcn_mfma_f32_16x16x32_bf16(a, bz, aZ[cf], 0, 0, 0);
      aR[cf] = __builtin_amdgcn_mfma_f32_16x16x32_bf16(a, br, aR[cf], 0, 0, 0);
    }
  }
  #pragma unroll
  for (int cf = 0; cf < 4; ++cf) {
    #pragma unroll
    for (int r = 0; r < 4; ++r) {
      Zs[q * 4 + r][w * 64 + cf * 16 + m] = aZ[cf][r];
      Rs[q * 4 + r][w * 64 + cf * 16 + m] = aR[cf][r];
    }
  }
  __syncthreads();

  #pragma unroll
  for (int rr = w; rr < 16; rr += 4) {
    float s = 0.f, sq = 0.f;
    #pragma unroll
    for (int p = 0; p < 4; ++p) {
      const float v = Zs[rr][l + 64 * p];
      s += v;
      sq = fmaf(v, v, sq);
    }
    #pragma unroll
    for (int off = 32; off; off >>= 1) {
      s += __shfl_down(s, off);
      sq += __shfl_down(sq, off);
    }
    if (l == 0) {
      const float mu = s * (1.0f / 256.0f);
      const float var = sq * (1.0f / 256.0f) - mu * mu;
      mu_s[rr] = mu;
      rs_s[rr] = rsqrtf(var + 1e-5f);
    }
  }
  __syncthreads();

  {
    const int t = threadIdx.x;
    const float g = gamma[t], be = beta[t];
    u16x8 o0, o1;
    #pragma unroll
    for (int rr = 0; rr < 16; ++rr) {
      Zb[(size_t)(k0 + rr) * D256 + t] = (Zs[rr][t] - mu_s[rr]) * rs_s[rr] * g + be;
      const unsigned short rb = f2bf(Rs[rr][t]);
      if (rr < 8) o0[rr] = rb; else o1[rr - 8] = rb;
    }
    unsigned short* dst = Bt + (size_t)t * 4096 + 2048 + k0;
    *(u16x8*)dst = o0;
    *(u16x8*)(dst + 8) = o1;
  }
}

// ---------------- k_B: cos-einsum, paired Chebyshev ----------------
__global__ __launch_bounds__(256, 6) void k_B(const float* __restrict__ Zb,
                                              const float4* __restrict__ PIt4,
                                              unsigned short* __restrict__ Bt) {
  __shared__ float buf[5120];           // 20 KB
  const int tid = threadIdx.x;
  const int il = tid & 7;
  const int jg = tid >> 3;              // 0..31
  const int bid = blockIdx.x & 4095;    // x4 duplication
  const int ig = bid & 31;
  const int kt = bid >> 5;
  const int i0 = ig * 8;
  const int k0 = kt * 16;
  const int i  = i0 + il;

  #pragma unroll
  for (int r = 0; r < 16; ++r)
    buf[tid * 20 + r] = Zb[(size_t)(k0 + r) * D256 + tid];
  __syncthreads();

  f32x2 acc[8];
  #pragma unroll
  for (int q = 0; q < 8; ++q) acc[q] = (f32x2){0.f, 0.f};

  const float kf0 = (float)k0;
  const f32x4* pip = (const f32x4*)(PIt4 + i);
  #pragma unroll
  for (int jj = 0; jj < 8; ++jj) {
    const int j = jg + 32 * jj;
    const f32x4 pi = pip[(size_t)j * D256];        // {P, 1/p, cb2, D}
    const float4 z0 = *(const float4*)&buf[j * 20 + 0];
    const float4 z1 = *(const float4*)&buf[j * 20 + 4];
    const float4 z2 = *(const float4*)&buf[j * 20 + 8];
    const float4 z3 = *(const float4*)&buf[j * 20 + 12];
    const float a  = kf0 * pi.y;
    const float r0 = __builtin_amdgcn_fractf(a);
    const float r1 = __builtin_amdgcn_fractf(a + pi.y);
    const float s0 = __builtin_amdgcn_cosf(r0) * pi.x;
    const float s1 = __builtin_amdgcn_cosf(r1) * pi.x;
    const float s2 = fmaf(pi.z, s1, -s0);
    const float s3 = fmaf(pi.z, s2, -s1);
    f32x2 P0 = {s0, s1};
    f32x2 P1 = {s2, s3};
    const f32x2 D2 = {pi.w, pi.w};
    acc[0] = __builtin_elementwise_fma((f32x2){z0.x, z0.y}, P0, acc[0]);
    acc[1] = __builtin_elementwise_fma((f32x2){z0.z, z0.w}, P1, acc[1]);
    f32x2 Pn;
#define CSTEP(IDX, ZA, ZB) \
    Pn = __builtin_elementwise_fma(D2, P1, -P0); \
    acc[IDX] = __builtin_elementwise_fma((f32x2){ZA, ZB}, Pn, acc[IDX]); \
    P0 = P1; P1 = Pn;
    CSTEP(2, z1.x, z1.y)
    CSTEP(3, z1.z, z1.w)
    CSTEP(4, z2.x, z2.y)
    CSTEP(5, z2.z, z2.w)
    CSTEP(6, z3.x, z3.y)
    CSTEP(7, z3.z, z3.w)
#undef CSTEP
  }
  __syncthreads();

  #pragma unroll
  for (int k2 = 0; k2 < 8; ++k2) {
    buf[jg * 132 + (k2 * 2) * 8 + il]     = acc[k2].x;
    buf[jg * 132 + (k2 * 2 + 1) * 8 + il] = acc[k2].y;
  }
  __syncthreads();

  float tv = 0.f;
  if (tid < 128) {
    #pragma unroll
    for (int g = 0; g < 32; ++g) tv += buf[g * 132 + tid];
  }
  __syncthreads();
  if (tid < 128) buf[(tid & 7) * 16 + (tid >> 3)] = tv;
  __syncthreads();
  if (tid < 32) {
    const int iw = tid >> 2;
    const int kq = tid & 3;
    const float4 v = *(const float4*)&buf[iw * 16 + kq * 4];
    u16x4 o;
    o[0] = f2bf(v.x); o[1] = f2bf(v.y); o[2] = f2bf(v.z); o[3] = f2bf(v.w);
    *(u16x4*)(Bt + (size_t)(i0 + iw) * 4096 + k0 + kq * 4) = o;
  }
}

// ---------------- k_Cm: bf16 MFMA GEMM, K split 8 ways ----------------
__global__ __launch_bounds__(256) void k_Cm(const unsigned short* __restrict__ LinkTb,
                                            const unsigned short* __restrict__ Bt,
                                            float* __restrict__ part) {
  const int bid = blockIdx.x & 511;     // x4 duplication
  const int kc = bid & 7;
  const int dt = (bid >> 3) & 3;
  const int tt = (bid >> 5) & 7;
  const int b  = bid >> 8;
  const int wv = threadIdx.x >> 6;
  const int l  = threadIdx.x & 63;
  const int wm = wv >> 1, wn = wv & 1;
  const int t0 = tt * 64 + wm * 32;
  const int d0 = dt * 64 + wn * 32;
  const int m  = l & 15;
  const int q  = l >> 4;
  const int sc0 = kc * 128;

  f32x4 acc00 = {}, acc01 = {}, acc10 = {}, acc11 = {};
  const unsigned short* Arow = LinkTb + (size_t)(t0 + m) * 2048;
  const unsigned short* Brow = Bt + (size_t)(d0 + m) * 4096;

  #pragma unroll
  for (int seg = 0; seg < 2; ++seg) {
    const int acol = seg * 1024 + sc0 + q * 8;
    const int bcol = seg * 2048 + b * 1024 + sc0 + q * 8;
    #pragma unroll
    for (int ks = 0; ks < 4; ++ks) {
      const bf16x8 a0 = *(const bf16x8*)(Arow + acol + ks * 32);
      const bf16x8 a1 = *(const bf16x8*)(Arow + 16 * 2048 + acol + ks * 32);
      const bf16x8 b0 = *(const bf16x8*)(Brow + bcol + ks * 32);
      const bf16x8 b1 = *(const bf16x8*)(Brow + 16 * 4096 + bcol + ks * 32);
      acc00 = __builtin_amdgcn_mfma_f32_16x16x32_bf16(a0, b0, acc00, 0, 0, 0);
      acc01 = __builtin_amdgcn_mfma_f32_16x16x32_bf16(a0, b1, acc01, 0, 0, 0);
      acc10 = __builtin_amdgcn_mfma_f32_16x16x32_bf16(a1, b0, acc10, 0, 0, 0);
      acc11 = __builtin_amdgcn_mfma_f32_16x16x32_bf16(a1, b1, acc11, 0, 0, 0);
    }
  }

  float* pb = part + ((size_t)kc << 18) + (size_t)(b * 512 + t0 + q * 4) * D256 + d0 + m;
  #pragma unroll
  for (int reg = 0; reg < 4; ++reg) {
    pb[(0 + reg) * D256 + 0]   = acc00[reg];
    pb[(0 + reg) * D256 + 16]  = acc01[reg];
    pb[(16 + reg) * D256 + 0]  = acc10[reg];
    pb[(16 + reg) * D256 + 16] = acc11[reg];
  }
}

// ---------------- k_Cred: sum the 8 K-chunk partials ----------------
__global__ __launch_bounds__(256) void k_Cred(const float* __restrict__ part,
                                              float* __restrict__ out) {
  const int row = blockIdx.x & 1023;    // x4 duplication
  const int d   = threadIdx.x;
  float s = 0.f;
  #pragma unroll
  for (int kc = 0; kc < 8; ++kc)
    s += part[((size_t)kc << 18) + row * D256 + d];
  out[row * D256 + d] = s;
}

extern "C" void kernel_launch(void* const* d_in, const int* in_sizes, int n_in,
                              void* d_out, int out_size, void* d_ws, size_t ws_size,
                              hipStream_t stream) {
  const float* x       = (const float*)d_in[0];
  const float* M       = (const float*)d_in[1];
  const float* P       = (const float*)d_in[2];
  const float* Linker  = (const float*)d_in[3];
  const float* gamma   = (const float*)d_in[4];
  const float* beta    = (const float*)d_in[5];
  const float* resW    = (const float*)d_in[6];
  const float* rLinker = (const float*)d_in[7];
  float* out = (float*)d_out;

  char* ws = (char*)d_ws;
  float4*         PIt4   = (float4*)(ws);                           // 1 MB
  unsigned short* LinkTb = (unsigned short*)(ws + 1024 * 1024);     // 2 MB
  unsigned short* Bt     = (unsigned short*)(ws + 3072 * 1024);     // 2 MB
  unsigned short* xb     = (unsigned short*)(ws + 5120 * 1024);     // 1 MB
  unsigned short* Mb     = (unsigned short*)(ws + 6144 * 1024);     // 128 KB
  unsigned short* Wb     = (unsigned short*)(ws + 6272 * 1024);     // 128 KB
  float*          Zb     = (float*)(ws + 6400 * 1024);              // 2 MB
  float*          part   = (float*)(ws + 8448 * 1024);              // 8 MB

  hipLaunchKernelGGL(k_prep, dim3(3328),  dim3(256), 0, stream,
                     x, M, resW, P, Linker, rLinker, PIt4, LinkTb, xb, Mb, Wb);
  hipLaunchKernelGGL(k_Azn,  dim3(512),   dim3(256), 0, stream,
                     xb, Mb, Wb, gamma, beta, Zb, Bt);
  hipLaunchKernelGGL(k_B,    dim3(16384), dim3(256), 0, stream, Zb, PIt4, Bt);
  hipLaunchKernelGGL(k_Cm,   dim3(2048),  dim3(256), 0, stream, LinkTb, Bt, part);
  hipLaunchKernelGGL(k_Cred, dim3(4096),  dim3(256), 0, stream, part, out);
}

// Round 16
// 54.445 us; speedup vs baseline: 2.1339x; 2.1339x over previous
//
#include <hip/hip_runtime.h>

#define D256 256
#define S_SEQ 1024
#define OUTSEQ 512

typedef __attribute__((ext_vector_type(8))) short bf16x8;
typedef __attribute__((ext_vector_type(8))) unsigned short u16x8;
typedef __attribute__((ext_vector_type(4))) unsigned short u16x4;
typedef __attribute__((ext_vector_type(4))) float f32x4;
typedef __attribute__((ext_vector_type(2))) float f32x2;

__device__ inline unsigned short f2bf(float f) {          // RNE fp32->bf16
  unsigned u = __float_as_uint(f);
  return (unsigned short)((u + 0x7fffu + ((u >> 16) & 1u)) >> 16);
}

__device__ inline bf16x8 ld8bf(const float* p) {          // load 8 fp32, pack bf16x8
  const float4 v0 = *(const float4*)p;
  const float4 v1 = *(const float4*)(p + 4);
  bf16x8 r;
  r[0] = (short)f2bf(v0.x); r[1] = (short)f2bf(v0.y);
  r[2] = (short)f2bf(v0.z); r[3] = (short)f2bf(v0.w);
  r[4] = (short)f2bf(v1.x); r[5] = (short)f2bf(v1.y);
  r[6] = (short)f2bf(v1.z); r[7] = (short)f2bf(v1.w);
  return r;
}

// ---------------- k_pre: one dispatch, three independent jobs ----------------
// blocks   0..127 : Azn — Zpre=x@M^T (MFMA, in-reg bf16 cvt) -> LN -> Zb fp32;
//                   rfeat=x@resW^T -> Bt[d][2048+k] bf16
// blocks 128..383 : PIt4[j][i] = {P[i][j], 1/p, cb2, D}, p = i*256+j+2
// blocks 384..639 : LinkTb[t][s] = bf16( s<1024 ? Linker[s][t] : rLinker[s-1024][t] )
__global__ __launch_bounds__(256) void k_pre(const float* __restrict__ x,
                                             const float* __restrict__ M,
                                             const float* __restrict__ resW,
                                             const float* __restrict__ P,
                                             const float* __restrict__ Linker,
                                             const float* __restrict__ rLinker,
                                             const float* __restrict__ gamma,
                                             const float* __restrict__ beta,
                                             float4* __restrict__ PIt4,
                                             unsigned short* __restrict__ LinkTb,
                                             float* __restrict__ Zb,
                                             unsigned short* __restrict__ Bt) {
  __shared__ float smem[8224];          // 32.9 KB, aliased per path
  const int tid = threadIdx.x;
  const int blk = blockIdx.x;

  if (blk < 128) {
    // ---------------- Azn path ----------------
    float (*Zs)[D256] = (float(*)[D256])smem;
    float (*Rs)[D256] = (float(*)[D256])(smem + 4096);
    float* mu_s = smem + 8192;
    float* rs_s = smem + 8208;
    const int k0 = blk * 16;
    const int w = tid >> 6;
    const int l = tid & 63;
    const int m = l & 15, q = l >> 4;

    f32x4 aZ[4] = {}, aR[4] = {};
    const float* xrow = x + (size_t)(k0 + m) * D256;
    #pragma unroll
    for (int ks = 0; ks < 8; ++ks) {
      const bf16x8 a = ld8bf(xrow + ks * 32 + q * 8);
      #pragma unroll
      for (int cf = 0; cf < 4; ++cf) {
        const int o = w * 64 + cf * 16 + m;
        const bf16x8 bz = ld8bf(M    + (size_t)o * D256 + ks * 32 + q * 8);
        const bf16x8 br = ld8bf(resW + (size_t)o * D256 + ks * 32 + q * 8);
        aZ[cf] = __builtin_amdgcn_mfma_f32_16x16x32_bf16(a, bz, aZ[cf], 0, 0, 0);
        aR[cf] = __builtin_amdgcn_mfma_f32_16x16x32_bf16(a, br, aR[cf], 0, 0, 0);
      }
    }
    #pragma unroll
    for (int cf = 0; cf < 4; ++cf) {
      #pragma unroll
      for (int r = 0; r < 4; ++r) {
        Zs[q * 4 + r][w * 64 + cf * 16 + m] = aZ[cf][r];
        Rs[q * 4 + r][w * 64 + cf * 16 + m] = aR[cf][r];
      }
    }
    __syncthreads();

    // LN stats: wave w reduces rows {w, w+4, w+8, w+12}
    #pragma unroll
    for (int rr = w; rr < 16; rr += 4) {
      float s = 0.f, sq = 0.f;
      #pragma unroll
      for (int p = 0; p < 4; ++p) {
        const float v = Zs[rr][l + 64 * p];
        s += v;
        sq = fmaf(v, v, sq);
      }
      #pragma unroll
      for (int off = 32; off; off >>= 1) {
        s += __shfl_down(s, off);
        sq += __shfl_down(sq, off);
      }
      if (l == 0) {
        const float mu = s * (1.0f / 256.0f);
        const float var = sq * (1.0f / 256.0f) - mu * mu;
        mu_s[rr] = mu;
        rs_s[rr] = rsqrtf(var + 1e-5f);
      }
    }
    __syncthreads();

    // normalize -> Zb fp32; pack rfeat -> Bt bf16 transposed
    {
      const int t = tid;
      const float g = gamma[t], be = beta[t];
      u16x8 o0, o1;
      #pragma unroll
      for (int rr = 0; rr < 16; ++rr) {
        Zb[(size_t)(k0 + rr) * D256 + t] = (Zs[rr][t] - mu_s[rr]) * rs_s[rr] * g + be;
        const unsigned short rb = f2bf(Rs[rr][t]);
        if (rr < 8) o0[rr] = rb; else o1[rr - 8] = rb;
      }
      unsigned short* dst = Bt + (size_t)t * 4096 + 2048 + k0;
      *(u16x8*)dst = o0;
      *(u16x8*)(dst + 8) = o1;
    }
    return;
  }

  if (blk < 384) {
    // ---------------- PIt4 path ----------------
    const int j = blk - 128;
    const int t = tid;
    const float p = (float)(t * D256 + j + 2);
    const float ip = 1.0f / p;
    const float cb2 = 2.0f * __builtin_amdgcn_cosf(ip);   // v_cos takes revolutions
    const float D = fmaf(cb2, cb2, -2.0f);                // 2cos(4pi/p)
    PIt4[j * D256 + t] = make_float4(P[t * D256 + j], ip, cb2, D);
    return;
  }

  // ---------------- LinkTb transpose-pack path ----------------
  float (*tl)[65] = (float(*)[65])smem;                   // 64*65 floats
  const int tb = blk - 384;             // 0..255
  const int st = tb & 31;               // s-tile (64 rows)
  const int tt = tb >> 5;               // t-tile (64 cols)
  const int s0 = st * 64, t0 = tt * 64;
  const float* src = (s0 < 1024) ? (Linker + (size_t)s0 * OUTSEQ)
                                 : (rLinker + (size_t)(s0 - 1024) * OUTSEQ);
  {
    const int sy = tid >> 2, sx = tid & 3;
    #pragma unroll
    for (int c = 0; c < 4; ++c) {
      const int ci = sx + c * 4;
      const float4 v = *(const float4*)&src[sy * OUTSEQ + t0 + ci * 4];
      tl[ci * 4 + 0][sy] = v.x;
      tl[ci * 4 + 1][sy] = v.y;
      tl[ci * 4 + 2][sy] = v.z;
      tl[ci * 4 + 3][sy] = v.w;
    }
  }
  __syncthreads();
  {
    const int ty = tid >> 2, tx = tid & 3;
    u16x8 o0, o1;
    #pragma unroll
    for (int e = 0; e < 8; ++e) o0[e] = f2bf(tl[ty][tx * 16 + e]);
    #pragma unroll
    for (int e = 0; e < 8; ++e) o1[e] = f2bf(tl[ty][tx * 16 + 8 + e]);
    unsigned short* dst = LinkTb + (size_t)(t0 + ty) * 2048 + s0 + tx * 16;
    *(u16x8*)dst = o0;
    *(u16x8*)(dst + 8) = o1;
  }
}

// ---------------- k_B: cos-einsum, paired Chebyshev (R14 proven) ----------------
// grid 4096 = kt(128) x ig(32); 256 thr = jg(32) x il(8);
// thread: i = ig*8+il, j in {jg + 32*jj}; 16 k per tile as 8 f32x2 pairs.
// Pair recurrence: P_{m+1} = D*P_m - P_{m-1}, D = 2cos(4pi/p) (PIt4.w).
__global__ __launch_bounds__(256, 6) void k_B(const float* __restrict__ Zb,
                                              const float4* __restrict__ PIt4,
                                              unsigned short* __restrict__ Bt) {
  __shared__ float buf[5120];           // 20 KB
  const int tid = threadIdx.x;
  const int il = tid & 7;
  const int jg = tid >> 3;              // 0..31
  const int ig = blockIdx.x & 31;
  const int kt = blockIdx.x >> 5;
  const int i0 = ig * 8;
  const int k0 = kt * 16;
  const int i  = i0 + il;

  // stage Z tile: buf[j*20 + k] = Zb[k0+k][j]   (coalesced global reads)
  #pragma unroll
  for (int r = 0; r < 16; ++r)
    buf[tid * 20 + r] = Zb[(size_t)(k0 + r) * D256 + tid];
  __syncthreads();

  f32x2 acc[8];
  #pragma unroll
  for (int q = 0; q < 8; ++q) acc[q] = (f32x2){0.f, 0.f};

  const float kf0 = (float)k0;
  const f32x4* pip = (const f32x4*)(PIt4 + i);
  #pragma unroll
  for (int jj = 0; jj < 8; ++jj) {
    const int j = jg + 32 * jj;                    // stride-32 j: bank-clean b128 reads
    const f32x4 pi = pip[(size_t)j * D256];        // {P, 1/p, cb2, D}
    const float4 z0 = *(const float4*)&buf[j * 20 + 0];   // 8-lane broadcast groups
    const float4 z1 = *(const float4*)&buf[j * 20 + 4];
    const float4 z2 = *(const float4*)&buf[j * 20 + 8];
    const float4 z3 = *(const float4*)&buf[j * 20 + 12];
    const float a  = kf0 * pi.y;
    const float r0 = __builtin_amdgcn_fractf(a);
    const float r1 = __builtin_amdgcn_fractf(a + pi.y);
    const float s0 = __builtin_amdgcn_cosf(r0) * pi.x;    // P folded into seeds
    const float s1 = __builtin_amdgcn_cosf(r1) * pi.x;
    const float s2 = fmaf(pi.z, s1, -s0);
    const float s3 = fmaf(pi.z, s2, -s1);
    f32x2 P0 = {s0, s1};
    f32x2 P1 = {s2, s3};
    const f32x2 D2 = {pi.w, pi.w};
    acc[0] = __builtin_elementwise_fma((f32x2){z0.x, z0.y}, P0, acc[0]);
    acc[1] = __builtin_elementwise_fma((f32x2){z0.z, z0.w}, P1, acc[1]);
    f32x2 Pn;
#define CSTEP(IDX, ZA, ZB) \
    Pn = __builtin_elementwise_fma(D2, P1, -P0); \
    acc[IDX] = __builtin_elementwise_fma((f32x2){ZA, ZB}, Pn, acc[IDX]); \
    P0 = P1; P1 = Pn;
    CSTEP(2, z1.x, z1.y)
    CSTEP(3, z1.z, z1.w)
    CSTEP(4, z2.x, z2.y)
    CSTEP(5, z2.z, z2.w)
    CSTEP(6, z3.x, z3.y)
    CSTEP(7, z3.z, z3.w)
#undef CSTEP
  }
  __syncthreads();                      // Z reads done; reuse buf as red

  #pragma unroll
  for (int k2 = 0; k2 < 8; ++k2) {
    buf[jg * 132 + (k2 * 2) * 8 + il]     = acc[k2].x;
    buf[jg * 132 + (k2 * 2 + 1) * 8 + il] = acc[k2].y;
  }
  __syncthreads();

  float tv = 0.f;
  if (tid < 128) {                      // tid = k*8 + il
    #pragma unroll
    for (int g = 0; g < 32; ++g) tv += buf[g * 132 + tid];
  }
  __syncthreads();
  if (tid < 128) buf[(tid & 7) * 16 + (tid >> 3)] = tv;   // outT[il][k]
  __syncthreads();
  if (tid < 32) {
    const int iw = tid >> 2;
    const int kq = tid & 3;
    const float4 v = *(const float4*)&buf[iw * 16 + kq * 4];
    u16x4 o;
    o[0] = f2bf(v.x); o[1] = f2bf(v.y); o[2] = f2bf(v.z); o[3] = f2bf(v.w);
    *(u16x4*)(Bt + (size_t)(i0 + iw) * 4096 + k0 + kq * 4) = o;
  }
}

// ---------------- k_Cm: bf16 MFMA GEMM, direct out (R12 proven) ----------------
// grid 512 = b(2) x tt(32: 16-row tiles) x ct(8); 4 waves = (seg, s-half)
__global__ __launch_bounds__(256) void k_Cm(const unsigned short* __restrict__ LinkTb,
                                            const unsigned short* __restrict__ Bt,
                                            float* __restrict__ out) {
  __shared__ float red[4][16][32];      // 8 KB
  const int bid = blockIdx.x;
  const int ct = bid & 7;
  const int tt = (bid >> 3) & 31;
  const int b  = bid >> 8;
  const int t0 = tt * 16;
  const int d0 = ct * 32;
  const int w  = threadIdx.x >> 6;
  const int l  = threadIdx.x & 63;
  const int m  = l & 15, q = l >> 4;
  const int seg = w >> 1;               // 0: Linker*T, 1: rLinker*rfeat
  const int sh  = w & 1;                // s-half within seg

  f32x4 acc0 = {}, acc1 = {};
  const unsigned short* Arow = LinkTb + (size_t)(t0 + m) * 2048 + seg * 1024 + sh * 512 + q * 8;
  const unsigned short* Brow = Bt + (size_t)(d0 + m) * 4096 + seg * 2048 + b * 1024 + sh * 512 + q * 8;

  #pragma unroll
  for (int ks = 0; ks < 16; ++ks) {
    const bf16x8 a0 = *(const bf16x8*)(Arow + ks * 32);
    const bf16x8 b0 = *(const bf16x8*)(Brow + ks * 32);
    const bf16x8 b1 = *(const bf16x8*)(Brow + 16 * 4096 + ks * 32);
    acc0 = __builtin_amdgcn_mfma_f32_16x16x32_bf16(a0, b0, acc0, 0, 0, 0);
    acc1 = __builtin_amdgcn_mfma_f32_16x16x32_bf16(a0, b1, acc1, 0, 0, 0);
  }

  #pragma unroll
  for (int r = 0; r < 4; ++r) {
    red[w][q * 4 + r][m]      = acc0[r];
    red[w][q * 4 + r][16 + m] = acc1[r];
  }
  __syncthreads();

  const int row = threadIdx.x >> 4;
  const int c0  = (threadIdx.x & 15) * 2;
  float2 s;
  s.x = red[0][row][c0] + red[1][row][c0] + red[2][row][c0] + red[3][row][c0];
  s.y = red[0][row][c0 + 1] + red[1][row][c0 + 1] + red[2][row][c0 + 1] + red[3][row][c0 + 1];
  *(float2*)&out[(size_t)(b * 512 + t0 + row) * D256 + d0 + c0] = s;
}

extern "C" void kernel_launch(void* const* d_in, const int* in_sizes, int n_in,
                              void* d_out, int out_size, void* d_ws, size_t ws_size,
                              hipStream_t stream) {
  const float* x       = (const float*)d_in[0];
  const float* M       = (const float*)d_in[1];
  const float* P       = (const float*)d_in[2];
  const float* Linker  = (const float*)d_in[3];
  const float* gamma   = (const float*)d_in[4];
  const float* beta    = (const float*)d_in[5];
  const float* resW    = (const float*)d_in[6];
  const float* rLinker = (const float*)d_in[7];
  float* out = (float*)d_out;

  char* ws = (char*)d_ws;
  float4*         PIt4   = (float4*)(ws);                           // 1 MB
  unsigned short* LinkTb = (unsigned short*)(ws + 1024 * 1024);     // 2 MB
  unsigned short* Bt     = (unsigned short*)(ws + 3072 * 1024);     // 2 MB
  float*          Zb     = (float*)(ws + 5120 * 1024);              // 2 MB

  hipLaunchKernelGGL(k_pre, dim3(640),  dim3(256), 0, stream,
                     x, M, resW, P, Linker, rLinker, gamma, beta,
                     PIt4, LinkTb, Zb, Bt);
  hipLaunchKernelGGL(k_B,   dim3(4096), dim3(256), 0, stream, Zb, PIt4, Bt);
  hipLaunchKernelGGL(k_Cm,  dim3(512),  dim3(256), 0, stream, LinkTb, Bt, out);
}

// Round 17
// 51.084 us; speedup vs baseline: 2.2742x; 1.0658x over previous
//
#include <hip/hip_runtime.h>
#include <hip/hip_cooperative_groups.h>

namespace cg = cooperative_groups;

#define D256 256
#define S_SEQ 1024
#define OUTSEQ 512

typedef __attribute__((ext_vector_type(8))) short bf16x8;
typedef __attribute__((ext_vector_type(8))) unsigned short u16x8;
typedef __attribute__((ext_vector_type(4))) unsigned short u16x4;
typedef __attribute__((ext_vector_type(4))) float f32x4;
typedef __attribute__((ext_vector_type(2))) float f32x2;

__device__ inline unsigned short f2bf(float f) {          // RNE fp32->bf16
  unsigned u = __float_as_uint(f);
  return (unsigned short)((u + 0x7fffu + ((u >> 16) & 1u)) >> 16);
}

// ================= phase bodies (shared by coop + fallback) =================

// blk 0..255: PIt4; 256..511: LinkTb; 512..767: xb; 768..799: Mb; 800..831: Wb
__device__ __forceinline__ void phase_prep(int blk, int tid, float* smem,
                                           const float* x, const float* M,
                                           const float* resW, const float* P,
                                           const float* Linker, const float* rLinker,
                                           float4* PIt4, unsigned short* LinkTb,
                                           unsigned short* xb, unsigned short* Mb,
                                           unsigned short* Wb) {
  if (blk < 256) {
    const int j = blk;
    const int t = tid;
    const float p = (float)(t * D256 + j + 2);
    const float ip = 1.0f / p;
    const float cb2 = 2.0f * __builtin_amdgcn_cosf(ip);   // v_cos takes revolutions
    const float D = fmaf(cb2, cb2, -2.0f);                // 2cos(4pi/p)
    PIt4[j * D256 + t] = make_float4(P[t * D256 + j], ip, cb2, D);
    return;
  }
  if (blk >= 512) {                     // flat fp32 -> bf16 converts
    const float* src;
    unsigned short* dst;
    size_t base;
    if (blk < 768)      { src = x;    dst = xb; base = (size_t)(blk - 512) * 2048; }
    else if (blk < 800) { src = M;    dst = Mb; base = (size_t)(blk - 768) * 2048; }
    else                { src = resW; dst = Wb; base = (size_t)(blk - 800) * 2048; }
    const size_t off = base + (size_t)tid * 8;
    const float4 v0 = *(const float4*)(src + off);
    const float4 v1 = *(const float4*)(src + off + 4);
    u16x8 o;
    o[0] = f2bf(v0.x); o[1] = f2bf(v0.y); o[2] = f2bf(v0.z); o[3] = f2bf(v0.w);
    o[4] = f2bf(v1.x); o[5] = f2bf(v1.y); o[6] = f2bf(v1.z); o[7] = f2bf(v1.w);
    *(u16x8*)(dst + off) = o;
    return;
  }
  // LinkTb transpose-pack: tl[64][65] in smem
  float (*tl)[65] = (float(*)[65])smem;
  const int tb = blk - 256;
  const int st = tb & 31;
  const int tt = tb >> 5;
  const int s0 = st * 64, t0 = tt * 64;
  const float* src = (s0 < 1024) ? (Linker + (size_t)s0 * OUTSEQ)
                                 : (rLinker + (size_t)(s0 - 1024) * OUTSEQ);
  {
    const int sy = tid >> 2, sx = tid & 3;
    #pragma unroll
    for (int c = 0; c < 4; ++c) {
      const int ci = sx + c * 4;
      const float4 v = *(const float4*)&src[sy * OUTSEQ + t0 + ci * 4];
      tl[ci * 4 + 0][sy] = v.x;
      tl[ci * 4 + 1][sy] = v.y;
      tl[ci * 4 + 2][sy] = v.z;
      tl[ci * 4 + 3][sy] = v.w;
    }
  }
  __syncthreads();
  {
    const int ty = tid >> 2, tx = tid & 3;
    u16x8 o0, o1;
    #pragma unroll
    for (int e = 0; e < 8; ++e) o0[e] = f2bf(tl[ty][tx * 16 + e]);
    #pragma unroll
    for (int e = 0; e < 8; ++e) o1[e] = f2bf(tl[ty][tx * 16 + 8 + e]);
    unsigned short* dst = LinkTb + (size_t)(t0 + ty) * 2048 + s0 + tx * 16;
    *(u16x8*)dst = o0;
    *(u16x8*)(dst + 8) = o1;
  }
}

// blk 0..127: MFMA phase A + LN (reads bf16 xb/Mb/Wb)
__device__ __forceinline__ void phase_azn(int blk, int tid, float* smem,
                                          const unsigned short* xb,
                                          const unsigned short* Mb,
                                          const unsigned short* Wb,
                                          const float* gamma, const float* beta,
                                          float* Zb, unsigned short* Bt) {
  float (*Zs)[D256] = (float(*)[D256])smem;
  float (*Rs)[D256] = (float(*)[D256])(smem + 4096);
  float* mu_s = smem + 8192;
  float* rs_s = smem + 8208;
  const int k0 = blk * 16;
  const int w = tid >> 6;
  const int l = tid & 63;
  const int m = l & 15, q = l >> 4;

  f32x4 aZ[4] = {}, aR[4] = {};
  const unsigned short* Arow = xb + (size_t)(k0 + m) * D256;
  #pragma unroll
  for (int ks = 0; ks < 8; ++ks) {
    const bf16x8 a = *(const bf16x8*)(Arow + ks * 32 + q * 8);
    #pragma unroll
    for (int cf = 0; cf < 4; ++cf) {
      const int o = w * 64 + cf * 16 + m;
      const bf16x8 bz = *(const bf16x8*)(Mb + (size_t)o * D256 + ks * 32 + q * 8);
      const bf16x8 br = *(const bf16x8*)(Wb + (size_t)o * D256 + ks * 32 + q * 8);
      aZ[cf] = __builtin_amdgcn_mfma_f32_16x16x32_bf16(a, bz, aZ[cf], 0, 0, 0);
      aR[cf] = __builtin_amdgcn_mfma_f32_16x16x32_bf16(a, br, aR[cf], 0, 0, 0);
    }
  }
  #pragma unroll
  for (int cf = 0; cf < 4; ++cf) {
    #pragma unroll
    for (int r = 0; r < 4; ++r) {
      Zs[q * 4 + r][w * 64 + cf * 16 + m] = aZ[cf][r];
      Rs[q * 4 + r][w * 64 + cf * 16 + m] = aR[cf][r];
    }
  }
  __syncthreads();

  #pragma unroll
  for (int rr = w; rr < 16; rr += 4) {
    float s = 0.f, sq = 0.f;
    #pragma unroll
    for (int p = 0; p < 4; ++p) {
      const float v = Zs[rr][l + 64 * p];
      s += v;
      sq = fmaf(v, v, sq);
    }
    #pragma unroll
    for (int off = 32; off; off >>= 1) {
      s += __shfl_down(s, off);
      sq += __shfl_down(sq, off);
    }
    if (l == 0) {
      const float mu = s * (1.0f / 256.0f);
      const float var = sq * (1.0f / 256.0f) - mu * mu;
      mu_s[rr] = mu;
      rs_s[rr] = rsqrtf(var + 1e-5f);
    }
  }
  __syncthreads();

  {
    const int t = tid;
    const float g = gamma[t], be = beta[t];
    u16x8 o0, o1;
    #pragma unroll
    for (int rr = 0; rr < 16; ++rr) {
      Zb[(size_t)(k0 + rr) * D256 + t] = (Zs[rr][t] - mu_s[rr]) * rs_s[rr] * g + be;
      const unsigned short rb = f2bf(Rs[rr][t]);
      if (rr < 8) o0[rr] = rb; else o1[rr - 8] = rb;
    }
    unsigned short* dst = Bt + (size_t)t * 4096 + 2048 + k0;
    *(u16x8*)dst = o0;
    *(u16x8*)(dst + 8) = o1;
  }
}

// all 1024 blocks: kt = bid>>3 (Z staged once), 4 ig-tiles per block
__device__ __forceinline__ void phase_b(int bid, int tid, float* smem,
                                        const float* Zb, const float4* PIt4,
                                        unsigned short* Bt) {
  float* buf  = smem;                   // 5120 floats: Z stage [j][20]
  float* rbuf = smem + 5120;            // 4224 floats: reduce area
  const int il = tid & 7;
  const int jg = tid >> 3;              // 0..31
  const int kt = bid >> 3;              // 0..127
  const int ig0 = (bid & 7) * 4;
  const int k0 = kt * 16;

  #pragma unroll
  for (int r = 0; r < 16; ++r)
    buf[tid * 20 + r] = Zb[(size_t)(k0 + r) * D256 + tid];
  __syncthreads();

  const float kf0 = (float)k0;
  #pragma unroll 1
  for (int v = 0; v < 4; ++v) {
    const int ig = ig0 + v;
    const int i0 = ig * 8;
    const int i  = i0 + il;

    f32x2 acc[8];
    #pragma unroll
    for (int q = 0; q < 8; ++q) acc[q] = (f32x2){0.f, 0.f};

    const f32x4* pip = (const f32x4*)(PIt4 + i);
    #pragma unroll
    for (int jj = 0; jj < 8; ++jj) {
      const int j = jg + 32 * jj;                  // stride-32 j: bank-clean b128
      const f32x4 pi = pip[(size_t)j * D256];      // {P, 1/p, cb2, D}
      const float4 z0 = *(const float4*)&buf[j * 20 + 0];
      const float4 z1 = *(const float4*)&buf[j * 20 + 4];
      const float4 z2 = *(const float4*)&buf[j * 20 + 8];
      const float4 z3 = *(const float4*)&buf[j * 20 + 12];
      const float a  = kf0 * pi.y;
      const float r0 = __builtin_amdgcn_fractf(a);
      const float r1 = __builtin_amdgcn_fractf(a + pi.y);
      const float s0 = __builtin_amdgcn_cosf(r0) * pi.x;  // P folded into seeds
      const float s1 = __builtin_amdgcn_cosf(r1) * pi.x;
      const float s2 = fmaf(pi.z, s1, -s0);
      const float s3 = fmaf(pi.z, s2, -s1);
      f32x2 P0 = {s0, s1};
      f32x2 P1 = {s2, s3};
      const f32x2 D2 = {pi.w, pi.w};
      acc[0] = __builtin_elementwise_fma((f32x2){z0.x, z0.y}, P0, acc[0]);
      acc[1] = __builtin_elementwise_fma((f32x2){z0.z, z0.w}, P1, acc[1]);
      f32x2 Pn;
#define CSTEP(IDX, ZA, ZB) \
      Pn = __builtin_elementwise_fma(D2, P1, -P0); \
      acc[IDX] = __builtin_elementwise_fma((f32x2){ZA, ZB}, Pn, acc[IDX]); \
      P0 = P1; P1 = Pn;
      CSTEP(2, z1.x, z1.y)
      CSTEP(3, z1.z, z1.w)
      CSTEP(4, z2.x, z2.y)
      CSTEP(5, z2.z, z2.w)
      CSTEP(6, z3.x, z3.y)
      CSTEP(7, z3.z, z3.w)
#undef CSTEP
    }

    #pragma unroll
    for (int k2 = 0; k2 < 8; ++k2) {
      rbuf[jg * 132 + (k2 * 2) * 8 + il]     = acc[k2].x;
      rbuf[jg * 132 + (k2 * 2 + 1) * 8 + il] = acc[k2].y;
    }
    __syncthreads();

    float tv = 0.f;
    if (tid < 128) {                    // tid = k*8 + il
      #pragma unroll
      for (int g = 0; g < 32; ++g) tv += rbuf[g * 132 + tid];
    }
    __syncthreads();
    if (tid < 128) rbuf[(tid & 7) * 16 + (tid >> 3)] = tv;   // outT[il][k]
    __syncthreads();
    if (tid < 32) {
      const int iw = tid >> 2;
      const int kq = tid & 3;
      const float4 vv = *(const float4*)&rbuf[iw * 16 + kq * 4];
      u16x4 o;
      o[0] = f2bf(vv.x); o[1] = f2bf(vv.y); o[2] = f2bf(vv.z); o[3] = f2bf(vv.w);
      *(u16x4*)(Bt + (size_t)(i0 + iw) * 4096 + k0 + kq * 4) = o;
    }
    __syncthreads();
  }
}

// blk 0..511: bf16 MFMA GEMM, direct out
__device__ __forceinline__ void phase_cm(int bid, int tid, float* smem,
                                         const unsigned short* LinkTb,
                                         const unsigned short* Bt,
                                         float* out) {
#define RED(w, r, c) smem[(((w) * 16 + (r)) * 32) + (c)]
  const int ct = bid & 7;
  const int tt = (bid >> 3) & 31;
  const int b  = bid >> 8;
  const int t0 = tt * 16;
  const int d0 = ct * 32;
  const int w  = tid >> 6;
  const int l  = tid & 63;
  const int m  = l & 15, q = l >> 4;
  const int seg = w >> 1;
  const int sh  = w & 1;

  f32x4 acc0 = {}, acc1 = {};
  const unsigned short* Arow = LinkTb + (size_t)(t0 + m) * 2048 + seg * 1024 + sh * 512 + q * 8;
  const unsigned short* Brow = Bt + (size_t)(d0 + m) * 4096 + seg * 2048 + b * 1024 + sh * 512 + q * 8;

  #pragma unroll
  for (int ks = 0; ks < 16; ++ks) {
    const bf16x8 a0 = *(const bf16x8*)(Arow + ks * 32);
    const bf16x8 b0 = *(const bf16x8*)(Brow + ks * 32);
    const bf16x8 b1 = *(const bf16x8*)(Brow + 16 * 4096 + ks * 32);
    acc0 = __builtin_amdgcn_mfma_f32_16x16x32_bf16(a0, b0, acc0, 0, 0, 0);
    acc1 = __builtin_amdgcn_mfma_f32_16x16x32_bf16(a0, b1, acc1, 0, 0, 0);
  }

  #pragma unroll
  for (int r = 0; r < 4; ++r) {
    RED(w, q * 4 + r, m)      = acc0[r];
    RED(w, q * 4 + r, 16 + m) = acc1[r];
  }
  __syncthreads();

  const int row = tid >> 4;
  const int c0  = (tid & 15) * 2;
  float2 s;
  s.x = RED(0, row, c0) + RED(1, row, c0) + RED(2, row, c0) + RED(3, row, c0);
  s.y = RED(0, row, c0 + 1) + RED(1, row, c0 + 1) + RED(2, row, c0 + 1) + RED(3, row, c0 + 1);
  *(float2*)&out[(size_t)(b * 512 + t0 + row) * D256 + d0 + c0] = s;
#undef RED
}

// ================= cooperative all-in-one =================
__global__ __launch_bounds__(256, 4) void k_all(const float* x, const float* M,
                                                const float* resW, const float* P,
                                                const float* Linker, const float* rLinker,
                                                const float* gamma, const float* beta,
                                                float4* PIt4, unsigned short* LinkTb,
                                                unsigned short* xb, unsigned short* Mb,
                                                unsigned short* Wb, float* Zb,
                                                unsigned short* Bt, float* out) {
  __shared__ float smem[9344];          // 37.4 KB -> 4 blocks/CU
  cg::grid_group grid = cg::this_grid();
  const int tid = threadIdx.x;
  const int bid = blockIdx.x;

  if (bid < 832)
    phase_prep(bid, tid, smem, x, M, resW, P, Linker, rLinker,
               PIt4, LinkTb, xb, Mb, Wb);
  grid.sync();

  if (bid < 128)
    phase_azn(bid, tid, smem, xb, Mb, Wb, gamma, beta, Zb, Bt);
  grid.sync();

  phase_b(bid, tid, smem, Zb, PIt4, Bt);
  grid.sync();

  if (bid < 512)
    phase_cm(bid, tid, smem, LinkTb, Bt, out);
}

// ================= fallback separate kernels =================
__global__ __launch_bounds__(256) void k_s_pre(const float* x, const float* M,
                                               const float* resW, const float* P,
                                               const float* Linker, const float* rLinker,
                                               float4* PIt4, unsigned short* LinkTb,
                                               unsigned short* xb, unsigned short* Mb,
                                               unsigned short* Wb) {
  __shared__ float smem[4160];
  phase_prep(blockIdx.x, threadIdx.x, smem, x, M, resW, P, Linker, rLinker,
             PIt4, LinkTb, xb, Mb, Wb);
}

__global__ __launch_bounds__(256) void k_s_azn(const unsigned short* xb,
                                               const unsigned short* Mb,
                                               const unsigned short* Wb,
                                               const float* gamma, const float* beta,
                                               float* Zb, unsigned short* Bt) {
  __shared__ float smem[8224];
  phase_azn(blockIdx.x, threadIdx.x, smem, xb, Mb, Wb, gamma, beta, Zb, Bt);
}

__global__ __launch_bounds__(256, 4) void k_s_b(const float* Zb, const float4* PIt4,
                                                unsigned short* Bt) {
  __shared__ float smem[9344];
  phase_b(blockIdx.x, threadIdx.x, smem, Zb, PIt4, Bt);
}

__global__ __launch_bounds__(256) void k_s_cm(const unsigned short* LinkTb,
                                              const unsigned short* Bt, float* out) {
  __shared__ float smem[2048];
  phase_cm(blockIdx.x, threadIdx.x, smem, LinkTb, Bt, out);
}

extern "C" void kernel_launch(void* const* d_in, const int* in_sizes, int n_in,
                              void* d_out, int out_size, void* d_ws, size_t ws_size,
                              hipStream_t stream) {
  const float* x       = (const float*)d_in[0];
  const float* M       = (const float*)d_in[1];
  const float* P       = (const float*)d_in[2];
  const float* Linker  = (const float*)d_in[3];
  const float* gamma   = (const float*)d_in[4];
  const float* beta    = (const float*)d_in[5];
  const float* resW    = (const float*)d_in[6];
  const float* rLinker = (const float*)d_in[7];
  float* out = (float*)d_out;

  char* ws = (char*)d_ws;
  float4*         PIt4   = (float4*)(ws);                           // 1 MB
  unsigned short* LinkTb = (unsigned short*)(ws + 1024 * 1024);     // 2 MB
  unsigned short* Bt     = (unsigned short*)(ws + 3072 * 1024);     // 2 MB
  unsigned short* xb     = (unsigned short*)(ws + 5120 * 1024);     // 1 MB
  unsigned short* Mb     = (unsigned short*)(ws + 6144 * 1024);     // 128 KB
  unsigned short* Wb     = (unsigned short*)(ws + 6272 * 1024);     // 128 KB
  float*          Zb     = (float*)(ws + 6400 * 1024);              // 2 MB

  int nb = 0;
  (void)hipOccupancyMaxActiveBlocksPerMultiprocessor(&nb, k_all, 256, 0);

  if (nb >= 4) {
    // 256 CU x 4 blocks/CU = 1024-block cooperative grid fits co-resident
    void* args[] = {(void*)&x, (void*)&M, (void*)&resW, (void*)&P,
                    (void*)&Linker, (void*)&rLinker, (void*)&gamma, (void*)&beta,
                    (void*)&PIt4, (void*)&LinkTb, (void*)&xb, (void*)&Mb,
                    (void*)&Wb, (void*)&Zb, (void*)&Bt, (void*)&out};
    hipLaunchCooperativeKernel(k_all, dim3(1024), dim3(256), args, 0, stream);
  } else {
    hipLaunchKernelGGL(k_s_pre, dim3(832),  dim3(256), 0, stream,
                       x, M, resW, P, Linker, rLinker, PIt4, LinkTb, xb, Mb, Wb);
    hipLaunchKernelGGL(k_s_azn, dim3(128),  dim3(256), 0, stream,
                       xb, Mb, Wb, gamma, beta, Zb, Bt);
    hipLaunchKernelGGL(k_s_b,   dim3(1024), dim3(256), 0, stream, Zb, PIt4, Bt);
    hipLaunchKernelGGL(k_s_cm,  dim3(512),  dim3(256), 0, stream, LinkTb, Bt, out);
  }
}

// Round 18
// 50.754 us; speedup vs baseline: 2.2890x; 1.0065x over previous
//
#include <hip/hip_runtime.h>

#define D256 256
#define S_SEQ 1024
#define OUTSEQ 512

typedef __attribute__((ext_vector_type(8))) short bf16x8;
typedef __attribute__((ext_vector_type(8))) unsigned short u16x8;
typedef __attribute__((ext_vector_type(4))) unsigned short u16x4;
typedef __attribute__((ext_vector_type(4))) float f32x4;
typedef __attribute__((ext_vector_type(2))) float f32x2;

__device__ inline unsigned short f2bf(float f) {          // RNE fp32->bf16
  unsigned u = __float_as_uint(f);
  return (unsigned short)((u + 0x7fffu + ((u >> 16) & 1u)) >> 16);
}

// ---------------- prep (R14 verbatim) ----------------
// blocks   0..255 : PIt4[j][i] = {P[i][j], 1/p, cb2, D}
// blocks 256..511 : LinkTb transpose-pack
// blocks 512..767 : xb = bf16(x)   768..799: Mb   800..831: Wb
__global__ __launch_bounds__(256) void k_prep(const float* __restrict__ x,
                                              const float* __restrict__ M,
                                              const float* __restrict__ resW,
                                              const float* __restrict__ P,
                                              const float* __restrict__ Linker,
                                              const float* __restrict__ rLinker,
                                              float4* __restrict__ PIt4,
                                              unsigned short* __restrict__ LinkTb,
                                              unsigned short* __restrict__ xb,
                                              unsigned short* __restrict__ Mb,
                                              unsigned short* __restrict__ Wb) {
  __shared__ float tl[64][65];
  const int tid = threadIdx.x;
  const int blk = blockIdx.x;
  if (blk < 256) {
    const int j = blk;
    const int t = tid;
    const float p = (float)(t * D256 + j + 2);
    const float ip = 1.0f / p;
    const float cb2 = 2.0f * __builtin_amdgcn_cosf(ip);   // v_cos takes revolutions
    const float D = fmaf(cb2, cb2, -2.0f);                // 2cos(4pi/p)
    PIt4[j * D256 + t] = make_float4(P[t * D256 + j], ip, cb2, D);
    return;
  }
  if (blk >= 512) {                     // flat fp32 -> bf16 converts
    const float* src;
    unsigned short* dst;
    size_t base;
    if (blk < 768)      { src = x;    dst = xb; base = (size_t)(blk - 512) * 2048; }
    else if (blk < 800) { src = M;    dst = Mb; base = (size_t)(blk - 768) * 2048; }
    else                { src = resW; dst = Wb; base = (size_t)(blk - 800) * 2048; }
    const size_t off = base + (size_t)tid * 8;
    const float4 v0 = *(const float4*)(src + off);
    const float4 v1 = *(const float4*)(src + off + 4);
    u16x8 o;
    o[0] = f2bf(v0.x); o[1] = f2bf(v0.y); o[2] = f2bf(v0.z); o[3] = f2bf(v0.w);
    o[4] = f2bf(v1.x); o[5] = f2bf(v1.y); o[6] = f2bf(v1.z); o[7] = f2bf(v1.w);
    *(u16x8*)(dst + off) = o;
    return;
  }
  const int tb = blk - 256;
  const int st = tb & 31;
  const int tt = tb >> 5;
  const int s0 = st * 64, t0 = tt * 64;
  const float* src = (s0 < 1024) ? (Linker + (size_t)s0 * OUTSEQ)
                                 : (rLinker + (size_t)(s0 - 1024) * OUTSEQ);
  {
    const int sy = tid >> 2, sx = tid & 3;
    #pragma unroll
    for (int c = 0; c < 4; ++c) {
      const int ci = sx + c * 4;
      const float4 v = *(const float4*)&src[sy * OUTSEQ + t0 + ci * 4];
      tl[ci * 4 + 0][sy] = v.x;
      tl[ci * 4 + 1][sy] = v.y;
      tl[ci * 4 + 2][sy] = v.z;
      tl[ci * 4 + 3][sy] = v.w;
    }
  }
  __syncthreads();
  {
    const int ty = tid >> 2, tx = tid & 3;
    u16x8 o0, o1;
    #pragma unroll
    for (int e = 0; e < 8; ++e) o0[e] = f2bf(tl[ty][tx * 16 + e]);
    #pragma unroll
    for (int e = 0; e < 8; ++e) o1[e] = f2bf(tl[ty][tx * 16 + 8 + e]);
    unsigned short* dst = LinkTb + (size_t)(t0 + ty) * 2048 + s0 + tx * 16;
    *(u16x8*)dst = o0;
    *(u16x8*)(dst + 8) = o1;
  }
}

// ---------------- k_Azn: MFMA phase A + LN (R14 verbatim) ----------------
__global__ __launch_bounds__(256) void k_Azn(const unsigned short* __restrict__ xb,
                                             const unsigned short* __restrict__ Mb,
                                             const unsigned short* __restrict__ Wb,
                                             const float* __restrict__ gamma,
                                             const float* __restrict__ beta,
                                             float* __restrict__ Zb,
                                             unsigned short* __restrict__ Bt) {
  __shared__ float Zs[16][D256];
  __shared__ float Rs[16][D256];
  __shared__ float mu_s[16], rs_s[16];
  const int k0 = blockIdx.x * 16;
  const int w = threadIdx.x >> 6;
  const int l = threadIdx.x & 63;
  const int m = l & 15, q = l >> 4;

  f32x4 aZ[4] = {}, aR[4] = {};
  const unsigned short* Arow = xb + (size_t)(k0 + m) * D256;
  #pragma unroll
  for (int ks = 0; ks < 8; ++ks) {
    const bf16x8 a = *(const bf16x8*)(Arow + ks * 32 + q * 8);
    #pragma unroll
    for (int cf = 0; cf < 4; ++cf) {
      const int o = w * 64 + cf * 16 + m;
      const bf16x8 bz = *(const bf16x8*)(Mb + (size_t)o * D256 + ks * 32 + q * 8);
      const bf16x8 br = *(const bf16x8*)(Wb + (size_t)o * D256 + ks * 32 + q * 8);
      aZ[cf] = __builtin_amdgcn_mfma_f32_16x16x32_bf16(a, bz, aZ[cf], 0, 0, 0);
      aR[cf] = __builtin_amdgcn_mfma_f32_16x16x32_bf16(a, br, aR[cf], 0, 0, 0);
    }
  }
  #pragma unroll
  for (int cf = 0; cf < 4; ++cf) {
    #pragma unroll
    for (int r = 0; r < 4; ++r) {
      Zs[q * 4 + r][w * 64 + cf * 16 + m] = aZ[cf][r];
      Rs[q * 4 + r][w * 64 + cf * 16 + m] = aR[cf][r];
    }
  }
  __syncthreads();

  #pragma unroll
  for (int rr = w; rr < 16; rr += 4) {
    float s = 0.f, sq = 0.f;
    #pragma unroll
    for (int p = 0; p < 4; ++p) {
      const float v = Zs[rr][l + 64 * p];
      s += v;
      sq = fmaf(v, v, sq);
    }
    #pragma unroll
    for (int off = 32; off; off >>= 1) {
      s += __shfl_down(s, off);
      sq += __shfl_down(sq, off);
    }
    if (l == 0) {
      const float mu = s * (1.0f / 256.0f);
      const float var = sq * (1.0f / 256.0f) - mu * mu;
      mu_s[rr] = mu;
      rs_s[rr] = rsqrtf(var + 1e-5f);
    }
  }
  __syncthreads();

  {
    const int t = threadIdx.x;
    const float g = gamma[t], be = beta[t];
    u16x8 o0, o1;
    #pragma unroll
    for (int rr = 0; rr < 16; ++rr) {
      Zb[(size_t)(k0 + rr) * D256 + t] = (Zs[rr][t] - mu_s[rr]) * rs_s[rr] * g + be;
      const unsigned short rb = f2bf(Rs[rr][t]);
      if (rr < 8) o0[rr] = rb; else o1[rr - 8] = rb;
    }
    unsigned short* dst = Bt + (size_t)t * 4096 + 2048 + k0;
    *(u16x8*)dst = o0;
    *(u16x8*)(dst + 8) = o1;
  }
}

// ---------------- k_B: paired Chebyshev, 4 ig-tiles share one Z-stage ------
// grid 1024 = kt(128) x igq(8); 256 thr = jg(32) x il(8); per v: ig = igq*4+v
__global__ __launch_bounds__(256, 4) void k_B(const float* __restrict__ Zb,
                                              const float4* __restrict__ PIt4,
                                              unsigned short* __restrict__ Bt) {
  __shared__ float buf[5120];           // Z stage [j][20]
  __shared__ float rbuf[4224];          // reduce area
  const int tid = threadIdx.x;
  const int il = tid & 7;
  const int jg = tid >> 3;              // 0..31
  const int kt = blockIdx.x >> 3;       // 0..127
  const int ig0 = (blockIdx.x & 7) * 4;
  const int k0 = kt * 16;

  #pragma unroll
  for (int r = 0; r < 16; ++r)
    buf[tid * 20 + r] = Zb[(size_t)(k0 + r) * D256 + tid];
  __syncthreads();

  const float kf0 = (float)k0;
  #pragma unroll 1
  for (int v = 0; v < 4; ++v) {
    const int i0 = (ig0 + v) * 8;
    const int i  = i0 + il;

    f32x2 acc[8];
    #pragma unroll
    for (int q = 0; q < 8; ++q) acc[q] = (f32x2){0.f, 0.f};

    const f32x4* pip = (const f32x4*)(PIt4 + i);
    #pragma unroll
    for (int jj = 0; jj < 8; ++jj) {
      const int j = jg + 32 * jj;                  // stride-32 j: bank-clean b128
      const f32x4 pi = pip[(size_t)j * D256];      // {P, 1/p, cb2, D}
      const float4 z0 = *(const float4*)&buf[j * 20 + 0];
      const float4 z1 = *(const float4*)&buf[j * 20 + 4];
      const float4 z2 = *(const float4*)&buf[j * 20 + 8];
      const float4 z3 = *(const float4*)&buf[j * 20 + 12];
      const float a  = kf0 * pi.y;
      const float r0 = __builtin_amdgcn_fractf(a);
      const float r1 = __builtin_amdgcn_fractf(a + pi.y);
      const float s0 = __builtin_amdgcn_cosf(r0) * pi.x;  // P folded into seeds
      const float s1 = __builtin_amdgcn_cosf(r1) * pi.x;
      const float s2 = fmaf(pi.z, s1, -s0);
      const float s3 = fmaf(pi.z, s2, -s1);
      f32x2 P0 = {s0, s1};
      f32x2 P1 = {s2, s3};
      const f32x2 D2 = {pi.w, pi.w};
      acc[0] = __builtin_elementwise_fma((f32x2){z0.x, z0.y}, P0, acc[0]);
      acc[1] = __builtin_elementwise_fma((f32x2){z0.z, z0.w}, P1, acc[1]);
      f32x2 Pn;
#define CSTEP(IDX, ZA, ZB) \
      Pn = __builtin_elementwise_fma(D2, P1, -P0); \
      acc[IDX] = __builtin_elementwise_fma((f32x2){ZA, ZB}, Pn, acc[IDX]); \
      P0 = P1; P1 = Pn;
      CSTEP(2, z1.x, z1.y)
      CSTEP(3, z1.z, z1.w)
      CSTEP(4, z2.x, z2.y)
      CSTEP(5, z2.z, z2.w)
      CSTEP(6, z3.x, z3.y)
      CSTEP(7, z3.z, z3.w)
#undef CSTEP
    }

    #pragma unroll
    for (int k2 = 0; k2 < 8; ++k2) {
      rbuf[jg * 132 + (k2 * 2) * 8 + il]     = acc[k2].x;
      rbuf[jg * 132 + (k2 * 2 + 1) * 8 + il] = acc[k2].y;
    }
    __syncthreads();

    float tv = 0.f;
    if (tid < 128) {                    // tid = k*8 + il
      #pragma unroll
      for (int g = 0; g < 32; ++g) tv += rbuf[g * 132 + tid];
    }
    __syncthreads();
    if (tid < 128) rbuf[(tid & 7) * 16 + (tid >> 3)] = tv;   // outT[il][k]
    __syncthreads();
    if (tid < 32) {
      const int iw = tid >> 2;
      const int kq = tid & 3;
      const float4 vv = *(const float4*)&rbuf[iw * 16 + kq * 4];
      u16x4 o;
      o[0] = f2bf(vv.x); o[1] = f2bf(vv.y); o[2] = f2bf(vv.z); o[3] = f2bf(vv.w);
      *(u16x4*)(Bt + (size_t)(i0 + iw) * 4096 + k0 + kq * 4) = o;
    }
    __syncthreads();
  }
}

// ---------------- k_Cm: bf16 MFMA GEMM, direct out (R16/R17 proven) --------
// grid 512 = b(2) x tt(32: 16-row tiles) x ct(8); 4 waves = (seg, s-half)
__global__ __launch_bounds__(256) void k_Cm(const unsigned short* __restrict__ LinkTb,
                                            const unsigned short* __restrict__ Bt,
                                            float* __restrict__ out) {
  __shared__ float red[4][16][32];      // 8 KB
  const int bid = blockIdx.x;
  const int ct = bid & 7;
  const int tt = (bid >> 3) & 31;
  const int b  = bid >> 8;
  const int t0 = tt * 16;
  const int d0 = ct * 32;
  const int w  = threadIdx.x >> 6;
  const int l  = threadIdx.x & 63;
  const int m  = l & 15, q = l >> 4;
  const int seg = w >> 1;               // 0: Linker*T, 1: rLinker*rfeat
  const int sh  = w & 1;                // s-half within seg

  f32x4 acc0 = {}, acc1 = {};
  const unsigned short* Arow = LinkTb + (size_t)(t0 + m) * 2048 + seg * 1024 + sh * 512 + q * 8;
  const unsigned short* Brow = Bt + (size_t)(d0 + m) * 4096 + seg * 2048 + b * 1024 + sh * 512 + q * 8;

  #pragma unroll
  for (int ks = 0; ks < 16; ++ks) {
    const bf16x8 a0 = *(const bf16x8*)(Arow + ks * 32);
    const bf16x8 b0 = *(const bf16x8*)(Brow + ks * 32);
    const bf16x8 b1 = *(const bf16x8*)(Brow + 16 * 4096 + ks * 32);
    acc0 = __builtin_amdgcn_mfma_f32_16x16x32_bf16(a0, b0, acc0, 0, 0, 0);
    acc1 = __builtin_amdgcn_mfma_f32_16x16x32_bf16(a0, b1, acc1, 0, 0, 0);
  }

  #pragma unroll
  for (int r = 0; r < 4; ++r) {
    red[w][q * 4 + r][m]      = acc0[r];
    red[w][q * 4 + r][16 + m] = acc1[r];
  }
  __syncthreads();

  const int row = threadIdx.x >> 4;
  const int c0  = (threadIdx.x & 15) * 2;
  float2 s;
  s.x = red[0][row][c0] + red[1][row][c0] + red[2][row][c0] + red[3][row][c0];
  s.y = red[0][row][c0 + 1] + red[1][row][c0 + 1] + red[2][row][c0 + 1] + red[3][row][c0 + 1];
  *(float2*)&out[(size_t)(b * 512 + t0 + row) * D256 + d0 + c0] = s;
}

extern "C" void kernel_launch(void* const* d_in, const int* in_sizes, int n_in,
                              void* d_out, int out_size, void* d_ws, size_t ws_size,
                              hipStream_t stream) {
  const float* x       = (const float*)d_in[0];
  const float* M       = (const float*)d_in[1];
  const float* P       = (const float*)d_in[2];
  const float* Linker  = (const float*)d_in[3];
  const float* gamma   = (const float*)d_in[4];
  const float* beta    = (const float*)d_in[5];
  const float* resW    = (const float*)d_in[6];
  const float* rLinker = (const float*)d_in[7];
  float* out = (float*)d_out;

  char* ws = (char*)d_ws;
  float4*         PIt4   = (float4*)(ws);                           // 1 MB
  unsigned short* LinkTb = (unsigned short*)(ws + 1024 * 1024);     // 2 MB
  unsigned short* Bt     = (unsigned short*)(ws + 3072 * 1024);     // 2 MB
  unsigned short* xb     = (unsigned short*)(ws + 5120 * 1024);     // 1 MB
  unsigned short* Mb     = (unsigned short*)(ws + 6144 * 1024);     // 128 KB
  unsigned short* Wb     = (unsigned short*)(ws + 6272 * 1024);     // 128 KB
  float*          Zb     = (float*)(ws + 6400 * 1024);              // 2 MB

  hipLaunchKernelGGL(k_prep, dim3(832),  dim3(256), 0, stream,
                     x, M, resW, P, Linker, rLinker, PIt4, LinkTb, xb, Mb, Wb);
  hipLaunchKernelGGL(k_Azn,  dim3(128),  dim3(256), 0, stream,
                     xb, Mb, Wb, gamma, beta, Zb, Bt);
  hipLaunchKernelGGL(k_B,    dim3(1024), dim3(256), 0, stream, Zb, PIt4, Bt);
  hipLaunchKernelGGL(k_Cm,   dim3(512),  dim3(256), 0, stream, LinkTb, Bt, out);
}

// Round 19
// 49.832 us; speedup vs baseline: 2.3314x; 1.0185x over previous
//
#include <hip/hip_runtime.h>

#define D256 256
#define S_SEQ 1024
#define OUTSEQ 512

typedef __attribute__((ext_vector_type(8))) short bf16x8;
typedef __attribute__((ext_vector_type(8))) unsigned short u16x8;
typedef __attribute__((ext_vector_type(4))) unsigned short u16x4;
typedef __attribute__((ext_vector_type(4))) float f32x4;
typedef __attribute__((ext_vector_type(2))) float f32x2;

__device__ inline unsigned short f2bf(float f) {          // RNE fp32->bf16
  unsigned u = __float_as_uint(f);
  return (unsigned short)((u + 0x7fffu + ((u >> 16) & 1u)) >> 16);
}

// ---------------- prep ----------------
// blocks   0..255 : PIt4[j][i] = {P[i][j], 1/p, cb2, D}, p = i*256+j+2
//                   cb2 = 2cos(2pi/p), D = cb2^2-2 = 2cos(4pi/p)
// blocks 256..511 : LinkTb[t][s] = bf16( s<1024 ? Linker[s][t] : rLinker[s-1024][t] )
// blocks 512..767 : xb = bf16(x)   768..799: Mb   800..831: Wb
__global__ __launch_bounds__(256) void k_prep(const float* __restrict__ x,
                                              const float* __restrict__ M,
                                              const float* __restrict__ resW,
                                              const float* __restrict__ P,
                                              const float* __restrict__ Linker,
                                              const float* __restrict__ rLinker,
                                              float4* __restrict__ PIt4,
                                              unsigned short* __restrict__ LinkTb,
                                              unsigned short* __restrict__ xb,
                                              unsigned short* __restrict__ Mb,
                                              unsigned short* __restrict__ Wb) {
  __shared__ float tl[64][65];
  const int tid = threadIdx.x;
  const int blk = blockIdx.x;
  if (blk < 256) {
    const int j = blk;
    const int t = tid;
    const float p = (float)(t * D256 + j + 2);
    const float ip = 1.0f / p;
    const float cb2 = 2.0f * __builtin_amdgcn_cosf(ip);   // v_cos takes revolutions
    const float D = fmaf(cb2, cb2, -2.0f);                // 2cos(4pi/p)
    PIt4[j * D256 + t] = make_float4(P[t * D256 + j], ip, cb2, D);
    return;
  }
  if (blk >= 512) {                     // flat fp32 -> bf16 converts
    const float* src;
    unsigned short* dst;
    size_t base;
    if (blk < 768)      { src = x;    dst = xb; base = (size_t)(blk - 512) * 2048; }
    else if (blk < 800) { src = M;    dst = Mb; base = (size_t)(blk - 768) * 2048; }
    else                { src = resW; dst = Wb; base = (size_t)(blk - 800) * 2048; }
    const size_t off = base + (size_t)tid * 8;
    const float4 v0 = *(const float4*)(src + off);
    const float4 v1 = *(const float4*)(src + off + 4);
    u16x8 o;
    o[0] = f2bf(v0.x); o[1] = f2bf(v0.y); o[2] = f2bf(v0.z); o[3] = f2bf(v0.w);
    o[4] = f2bf(v1.x); o[5] = f2bf(v1.y); o[6] = f2bf(v1.z); o[7] = f2bf(v1.w);
    *(u16x8*)(dst + off) = o;
    return;
  }
  // LinkTb transpose-pack
  const int tb = blk - 256;             // 0..255
  const int st = tb & 31;               // s-tile (64 rows)
  const int tt = tb >> 5;               // t-tile (64 cols)
  const int s0 = st * 64, t0 = tt * 64;
  const float* src = (s0 < 1024) ? (Linker + (size_t)s0 * OUTSEQ)
                                 : (rLinker + (size_t)(s0 - 1024) * OUTSEQ);
  {
    const int sy = tid >> 2, sx = tid & 3;
    #pragma unroll
    for (int c = 0; c < 4; ++c) {
      const int ci = sx + c * 4;
      const float4 v = *(const float4*)&src[sy * OUTSEQ + t0 + ci * 4];
      tl[ci * 4 + 0][sy] = v.x;
      tl[ci * 4 + 1][sy] = v.y;
      tl[ci * 4 + 2][sy] = v.z;
      tl[ci * 4 + 3][sy] = v.w;
    }
  }
  __syncthreads();
  {
    const int ty = tid >> 2, tx = tid & 3;
    u16x8 o0, o1;
    #pragma unroll
    for (int e = 0; e < 8; ++e) o0[e] = f2bf(tl[ty][tx * 16 + e]);
    #pragma unroll
    for (int e = 0; e < 8; ++e) o1[e] = f2bf(tl[ty][tx * 16 + 8 + e]);
    unsigned short* dst = LinkTb + (size_t)(t0 + ty) * 2048 + s0 + tx * 16;
    *(u16x8*)dst = o0;
    *(u16x8*)(dst + 8) = o1;
  }
}

// ---------------- k_Azn: MFMA phase A + LN ----------------
// grid 128 (k-tiles of 16), 256 thr = 4 waves; wave w owns o-cols [w*64, w*64+64)
// Zpre = x@M^T -> LN -> Zb fp32 [k][i];  rfeat = x@resW^T -> Bt[d][2048+k] bf16
__global__ __launch_bounds__(256) void k_Azn(const unsigned short* __restrict__ xb,
                                             const unsigned short* __restrict__ Mb,
                                             const unsigned short* __restrict__ Wb,
                                             const float* __restrict__ gamma,
                                             const float* __restrict__ beta,
                                             float* __restrict__ Zb,
                                             unsigned short* __restrict__ Bt) {
  __shared__ float Zs[16][D256];
  __shared__ float Rs[16][D256];
  __shared__ float mu_s[16], rs_s[16];
  const int k0 = blockIdx.x * 16;
  const int w = threadIdx.x >> 6;
  const int l = threadIdx.x & 63;
  const int m = l & 15, q = l >> 4;

  f32x4 aZ[4] = {}, aR[4] = {};
  const unsigned short* Arow = xb + (size_t)(k0 + m) * D256;
  #pragma unroll
  for (int ks = 0; ks < 8; ++ks) {
    const bf16x8 a = *(const bf16x8*)(Arow + ks * 32 + q * 8);
    #pragma unroll
    for (int cf = 0; cf < 4; ++cf) {
      const int o = w * 64 + cf * 16 + m;
      const bf16x8 bz = *(const bf16x8*)(Mb + (size_t)o * D256 + ks * 32 + q * 8);
      const bf16x8 br = *(const bf16x8*)(Wb + (size_t)o * D256 + ks * 32 + q * 8);
      aZ[cf] = __builtin_amdgcn_mfma_f32_16x16x32_bf16(a, bz, aZ[cf], 0, 0, 0);
      aR[cf] = __builtin_amdgcn_mfma_f32_16x16x32_bf16(a, br, aR[cf], 0, 0, 0);
    }
  }
  #pragma unroll
  for (int cf = 0; cf < 4; ++cf) {
    #pragma unroll
    for (int r = 0; r < 4; ++r) {
      Zs[q * 4 + r][w * 64 + cf * 16 + m] = aZ[cf][r];
      Rs[q * 4 + r][w * 64 + cf * 16 + m] = aR[cf][r];
    }
  }
  __syncthreads();

  // LN stats: wave w reduces rows {w, w+4, w+8, w+12}
  #pragma unroll
  for (int rr = w; rr < 16; rr += 4) {
    float s = 0.f, sq = 0.f;
    #pragma unroll
    for (int p = 0; p < 4; ++p) {
      const float v = Zs[rr][l + 64 * p];
      s += v;
      sq = fmaf(v, v, sq);
    }
    #pragma unroll
    for (int off = 32; off; off >>= 1) {
      s += __shfl_down(s, off);
      sq += __shfl_down(sq, off);
    }
    if (l == 0) {
      const float mu = s * (1.0f / 256.0f);
      const float var = sq * (1.0f / 256.0f) - mu * mu;
      mu_s[rr] = mu;
      rs_s[rr] = rsqrtf(var + 1e-5f);
    }
  }
  __syncthreads();

  // normalize -> Zb fp32; pack rfeat -> Bt bf16 transposed
  {
    const int t = threadIdx.x;
    const float g = gamma[t], be = beta[t];
    u16x8 o0, o1;
    #pragma unroll
    for (int rr = 0; rr < 16; ++rr) {
      Zb[(size_t)(k0 + rr) * D256 + t] = (Zs[rr][t] - mu_s[rr]) * rs_s[rr] * g + be;
      const unsigned short rb = f2bf(Rs[rr][t]);
      if (rr < 8) o0[rr] = rb; else o1[rr - 8] = rb;
    }
    unsigned short* dst = Bt + (size_t)t * 4096 + 2048 + k0;
    *(u16x8*)dst = o0;
    *(u16x8*)(dst + 8) = o1;
  }
}

// ---------------- k_B: cos-einsum, paired Chebyshev (pk-fma) ----------------
// R10 skeleton: grid 4096 = kt(128) x ig(32); 256 thr = jg(32) x il(8);
// thread: i = ig*8+il, j in {jg + 32*jj}; 16 k per tile as 8 f32x2 pairs.
// Pair recurrence: P_{m+1} = D*P_m - P_{m-1}, D = 2cos(4pi/p) (PIt4.w).
__global__ __launch_bounds__(256, 6) void k_B(const float* __restrict__ Zb,
                                              const float4* __restrict__ PIt4,
                                              unsigned short* __restrict__ Bt) {
  __shared__ float buf[5120];           // 20 KB
  const int tid = threadIdx.x;
  const int il = tid & 7;
  const int jg = tid >> 3;              // 0..31
  const int ig = blockIdx.x & 31;
  const int kt = blockIdx.x >> 5;
  const int i0 = ig * 8;
  const int k0 = kt * 16;
  const int i  = i0 + il;

  // stage Z tile: buf[j*20 + k] = Zb[k0+k][j]   (coalesced global reads)
  #pragma unroll
  for (int r = 0; r < 16; ++r)
    buf[tid * 20 + r] = Zb[(size_t)(k0 + r) * D256 + tid];
  __syncthreads();

  f32x2 acc[8];
  #pragma unroll
  for (int q = 0; q < 8; ++q) acc[q] = (f32x2){0.f, 0.f};

  const float kf0 = (float)k0;
  const f32x4* pip = (const f32x4*)(PIt4 + i);
  #pragma unroll
  for (int jj = 0; jj < 8; ++jj) {
    const int j = jg + 32 * jj;                    // stride-32 j: bank-clean b128 reads
    const f32x4 pi = pip[(size_t)j * D256];        // {P, 1/p, cb2, D}
    const float4 z0 = *(const float4*)&buf[j * 20 + 0];   // 8-lane broadcast groups
    const float4 z1 = *(const float4*)&buf[j * 20 + 4];
    const float4 z2 = *(const float4*)&buf[j * 20 + 8];
    const float4 z3 = *(const float4*)&buf[j * 20 + 12];
    const float a  = kf0 * pi.y;
    const float r0 = __builtin_amdgcn_fractf(a);
    const float r1 = __builtin_amdgcn_fractf(a + pi.y);
    const float s0 = __builtin_amdgcn_cosf(r0) * pi.x;    // P folded into seeds
    const float s1 = __builtin_amdgcn_cosf(r1) * pi.x;
    const float s2 = fmaf(pi.z, s1, -s0);
    const float s3 = fmaf(pi.z, s2, -s1);
    f32x2 P0 = {s0, s1};
    f32x2 P1 = {s2, s3};
    const f32x2 D2 = {pi.w, pi.w};
    acc[0] = __builtin_elementwise_fma((f32x2){z0.x, z0.y}, P0, acc[0]);
    acc[1] = __builtin_elementwise_fma((f32x2){z0.z, z0.w}, P1, acc[1]);
    f32x2 Pn;
#define CSTEP(IDX, ZA, ZB) \
    Pn = __builtin_elementwise_fma(D2, P1, -P0); \
    acc[IDX] = __builtin_elementwise_fma((f32x2){ZA, ZB}, Pn, acc[IDX]); \
    P0 = P1; P1 = Pn;
    CSTEP(2, z1.x, z1.y)
    CSTEP(3, z1.z, z1.w)
    CSTEP(4, z2.x, z2.y)
    CSTEP(5, z2.z, z2.w)
    CSTEP(6, z3.x, z3.y)
    CSTEP(7, z3.z, z3.w)
#undef CSTEP
  }
  __syncthreads();                      // Z reads done; reuse buf as red

  #pragma unroll
  for (int k2 = 0; k2 < 8; ++k2) {
    buf[jg * 132 + (k2 * 2) * 8 + il]     = acc[k2].x;
    buf[jg * 132 + (k2 * 2 + 1) * 8 + il] = acc[k2].y;
  }
  __syncthreads();

  float tv = 0.f;
  if (tid < 128) {                      // tid = k*8 + il
    #pragma unroll
    for (int g = 0; g < 32; ++g) tv += buf[g * 132 + tid];
  }
  __syncthreads();
  if (tid < 128) buf[(tid & 7) * 16 + (tid >> 3)] = tv;   // outT[il][k]
  __syncthreads();
  if (tid < 32) {
    const int iw = tid >> 2;
    const int kq = tid & 3;
    const float4 v = *(const float4*)&buf[iw * 16 + kq * 4];
    u16x4 o;
    o[0] = f2bf(v.x); o[1] = f2bf(v.y); o[2] = f2bf(v.z); o[3] = f2bf(v.w);
    *(u16x4*)(Bt + (size_t)(i0 + iw) * 4096 + k0 + kq * 4) = o;
  }
}

// ---------------- k_Cm: bf16 MFMA GEMM, K split 8 ways ----------------
__global__ __launch_bounds__(256) void k_Cm(const unsigned short* __restrict__ LinkTb,
                                            const unsigned short* __restrict__ Bt,
                                            float* __restrict__ part) {
  const int bid = blockIdx.x;
  const int kc = bid & 7;
  const int dt = (bid >> 3) & 3;
  const int tt = (bid >> 5) & 7;
  const int b  = bid >> 8;
  const int wv = threadIdx.x >> 6;
  const int l  = threadIdx.x & 63;
  const int wm = wv >> 1, wn = wv & 1;
  const int t0 = tt * 64 + wm * 32;
  const int d0 = dt * 64 + wn * 32;
  const int m  = l & 15;
  const int q  = l >> 4;
  const int sc0 = kc * 128;

  f32x4 acc00 = {}, acc01 = {}, acc10 = {}, acc11 = {};
  const unsigned short* Arow = LinkTb + (size_t)(t0 + m) * 2048;
  const unsigned short* Brow = Bt + (size_t)(d0 + m) * 4096;

  #pragma unroll
  for (int seg = 0; seg < 2; ++seg) {
    const int acol = seg * 1024 + sc0 + q * 8;
    const int bcol = seg * 2048 + b * 1024 + sc0 + q * 8;
    #pragma unroll
    for (int ks = 0; ks < 4; ++ks) {
      const bf16x8 a0 = *(const bf16x8*)(Arow + acol + ks * 32);
      const bf16x8 a1 = *(const bf16x8*)(Arow + 16 * 2048 + acol + ks * 32);
      const bf16x8 b0 = *(const bf16x8*)(Brow + bcol + ks * 32);
      const bf16x8 b1 = *(const bf16x8*)(Brow + 16 * 4096 + bcol + ks * 32);
      acc00 = __builtin_amdgcn_mfma_f32_16x16x32_bf16(a0, b0, acc00, 0, 0, 0);
      acc01 = __builtin_amdgcn_mfma_f32_16x16x32_bf16(a0, b1, acc01, 0, 0, 0);
      acc10 = __builtin_amdgcn_mfma_f32_16x16x32_bf16(a1, b0, acc10, 0, 0, 0);
      acc11 = __builtin_amdgcn_mfma_f32_16x16x32_bf16(a1, b1, acc11, 0, 0, 0);
    }
  }

  float* pb = part + ((size_t)kc << 18) + (size_t)(b * 512 + t0 + q * 4) * D256 + d0 + m;
  #pragma unroll
  for (int reg = 0; reg < 4; ++reg) {
    pb[(0 + reg) * D256 + 0]   = acc00[reg];
    pb[(0 + reg) * D256 + 16]  = acc01[reg];
    pb[(16 + reg) * D256 + 0]  = acc10[reg];
    pb[(16 + reg) * D256 + 16] = acc11[reg];
  }
}

// ---------------- k_Cred: sum the 8 K-chunk partials ----------------
__global__ __launch_bounds__(256) void k_Cred(const float* __restrict__ part,
                                              float* __restrict__ out) {
  const int row = blockIdx.x;   // 0..1023
  const int d   = threadIdx.x;
  float s = 0.f;
  #pragma unroll
  for (int kc = 0; kc < 8; ++kc)
    s += part[((size_t)kc << 18) + row * D256 + d];
  out[row * D256 + d] = s;
}

extern "C" void kernel_launch(void* const* d_in, const int* in_sizes, int n_in,
                              void* d_out, int out_size, void* d_ws, size_t ws_size,
                              hipStream_t stream) {
  const float* x       = (const float*)d_in[0];
  const float* M       = (const float*)d_in[1];
  const float* P       = (const float*)d_in[2];
  const float* Linker  = (const float*)d_in[3];
  const float* gamma   = (const float*)d_in[4];
  const float* beta    = (const float*)d_in[5];
  const float* resW    = (const float*)d_in[6];
  const float* rLinker = (const float*)d_in[7];
  float* out = (float*)d_out;

  char* ws = (char*)d_ws;
  float4*         PIt4   = (float4*)(ws);                           // 1 MB
  unsigned short* LinkTb = (unsigned short*)(ws + 1024 * 1024);     // 2 MB
  unsigned short* Bt     = (unsigned short*)(ws + 3072 * 1024);     // 2 MB
  unsigned short* xb     = (unsigned short*)(ws + 5120 * 1024);     // 1 MB
  unsigned short* Mb     = (unsigned short*)(ws + 6144 * 1024);     // 128 KB
  unsigned short* Wb     = (unsigned short*)(ws + 6272 * 1024);     // 128 KB
  float*          Zb     = (float*)(ws + 6400 * 1024);              // 2 MB
  float*          part   = (float*)(ws + 8448 * 1024);              // 8 MB

  hipLaunchKernelGGL(k_prep, dim3(832),  dim3(256), 0, stream,
                     x, M, resW, P, Linker, rLinker, PIt4, LinkTb, xb, Mb, Wb);
  hipLaunchKernelGGL(k_Azn,  dim3(128),  dim3(256), 0, stream,
                     xb, Mb, Wb, gamma, beta, Zb, Bt);
  hipLaunchKernelGGL(k_B,    dim3(4096), dim3(256), 0, stream, Zb, PIt4, Bt);
  hipLaunchKernelGGL(k_Cm,   dim3(512),  dim3(256), 0, stream, LinkTb, Bt, part);
  hipLaunchKernelGGL(k_Cred, dim3(1024), dim3(256), 0, stream, part, out);
}